// Round 2
// baseline (232.225 us; speedup 1.0000x reference)
//
#include <hip/hip_runtime.h>
#include <math.h>

#define TLEN 2048
#define DMODEL 2048
#define NHEADS 32
#define NKV 8
#define HDIM 64
#define KVDIM 512      // NKV * HDIM
#define WHALF 256      // WINDOW/2

typedef short shortx8 __attribute__((ext_vector_type(8)));
typedef float floatx4 __attribute__((ext_vector_type(4)));
typedef unsigned int uint32;

__device__ __forceinline__ unsigned short f2bf_rne(float x) {
    union { float f; uint32 u; } v; v.f = x;
    uint32 r = v.u + 0x7FFFu + ((v.u >> 16) & 1u);
    return (unsigned short)(r >> 16);
}

// async global->LDS, 16B per lane; LDS dst = wave-uniform base + lane*16
#define GL16(g, l)                                                              \
    __builtin_amdgcn_global_load_lds(                                           \
        (const __attribute__((address_space(1))) unsigned int*)(g),             \
        (__attribute__((address_space(3))) unsigned int*)(l), 16, 0, 0)

// ---------------------------------------------------------------------------
// One-time fp32 -> bf16: hs->hsb, {Wq,Wk,Wv}->Wcat[3072][2048], Wo->Wob.
// ---------------------------------------------------------------------------
__global__ __launch_bounds__(256) void convert_inputs(const float* __restrict__ hs,
                                                      const float* __restrict__ Wq,
                                                      const float* __restrict__ Wk,
                                                      const float* __restrict__ Wv,
                                                      const float* __restrict__ Wo,
                                                      unsigned short* __restrict__ hsb,
                                                      unsigned short* __restrict__ Wcat,
                                                      unsigned short* __restrict__ Wob) {
    int b = blockIdx.x;
    const float* src; unsigned short* dst;
    if (b < 512)       { src = hs; dst = hsb; }
    else if (b < 1024) { src = Wq; dst = Wcat;                           b -= 512; }
    else if (b < 1152) { src = Wk; dst = Wcat + (size_t)2048 * DMODEL;   b -= 1024; }
    else if (b < 1280) { src = Wv; dst = Wcat + (size_t)2560 * DMODEL;   b -= 1152; }
    else               { src = Wo; dst = Wob;                            b -= 1280; }
    size_t base = (size_t)b * 8192 + threadIdx.x * 4;
#pragma unroll
    for (int it = 0; it < 8; ++it) {
        size_t off = base + (size_t)it * 1024;
        float4 v = *(const float4*)(src + off);
        short4 p;
        p.x = (short)f2bf_rne(v.x); p.y = (short)f2bf_rne(v.y);
        p.z = (short)f2bf_rne(v.z); p.w = (short)f2bf_rne(v.w);
        *(short4*)(dst + off) = p;
    }
}

// ---------------------------------------------------------------------------
// Fused Q/K/V projection, pure bf16, 256x64 tile, BK=128 (m97 geometry:
// wave tile 64x64, acc 4x4, 64 MFMAs per wave per K-step).
// Grid (48, 8) = 384 blocks; LDS 80 KB -> 2 blocks/CU.
// LDS rows = 256B = 16 chunks of 16B; phys chunk = logical ^ (row&15)
// (4-bit XOR -> 4 lanes per 16B chunk on ds_read_b128 = conflict floor).
// ---------------------------------------------------------------------------
__global__ __launch_bounds__(256) void gemm_qkv(const unsigned short* __restrict__ hsb,
                                                const unsigned short* __restrict__ Wcat,
                                                unsigned short* __restrict__ Qo,
                                                unsigned short* __restrict__ Ko,
                                                unsigned short* __restrict__ Vo) {
    __shared__ short Ah[256][128];
    __shared__ short Bh[64][128];

    const int bnx = blockIdx.x;
    int mode, coff;   // 0=Q (32 tiles), 1=K (8), 2=V (8)
    if (bnx < 32)      { mode = 0; coff = bnx * 64; }
    else if (bnx < 40) { mode = 1; coff = (bnx - 32) * 64; }
    else               { mode = 2; coff = (bnx - 40) * 64; }
    const unsigned short* Bbase = Wcat + (size_t)bnx * 64 * DMODEL;

    const int bm = blockIdx.y * 256;
    const int tid = threadIdx.x;
    const int w = tid >> 6, lane = tid & 63;
    const int wA = w * 64, wB = w * 16;
    const int lr = lane & 15, quad = lane >> 4;
    const int r4 = lane >> 4;

    // staging: each GL16 covers rows 4g + r4; row&15 = 4*(g&3) + r4.
    // source logical chunk = phys(lane&15) ^ r4 ^ ((g&3)<<2)
    const unsigned short* Ag[4];
    const unsigned short* Bg[4];
#pragma unroll
    for (int gm = 0; gm < 4; ++gm) {
        const int cof = ((lane & 15) ^ r4 ^ (gm << 2)) * 8;
        Ag[gm] = hsb   + (size_t)(bm + wA + 4 * gm + r4) * DMODEL + cof;
        Bg[gm] = Bbase + (size_t)(wB + 4 * gm + r4) * DMODEL + cof;
    }

    floatx4 acc[4][4];
#pragma unroll
    for (int i = 0; i < 4; ++i)
#pragma unroll
        for (int j = 0; j < 4; ++j) acc[i][j] = (floatx4)0.0f;

    for (int k0 = 0; k0 < DMODEL; k0 += 128) {
        __syncthreads();
#pragma unroll
        for (int q = 0; q < 4; ++q)
#pragma unroll
            for (int gm = 0; gm < 4; ++gm)
                GL16(Ag[gm] + (size_t)(16 * q) * DMODEL + k0, &Ah[wA + 16 * q + 4 * gm][0]);
#pragma unroll
        for (int gm = 0; gm < 4; ++gm)
            GL16(Bg[gm] + k0, &Bh[wB + 4 * gm][0]);
        __syncthreads();

#pragma unroll
        for (int s = 0; s < 4; ++s) {
            const int cs = ((s * 4 + quad) ^ lr) * 8;
            shortx8 af[4], bf[4];
#pragma unroll
            for (int i = 0; i < 4; ++i) af[i] = *(shortx8*)&Ah[wA + i * 16 + lr][cs];
#pragma unroll
            for (int j = 0; j < 4; ++j) bf[j] = *(shortx8*)&Bh[j * 16 + lr][cs];
#pragma unroll
            for (int i = 0; i < 4; ++i)
#pragma unroll
                for (int j = 0; j < 4; ++j)
                    acc[i][j] = __builtin_amdgcn_mfma_f32_16x16x32_bf16(af[i], bf[j], acc[i][j], 0, 0, 0);
        }
    }

    // ---- fused RoPE (pair (d,d+32) = acc[i][j], acc[i][j+2], same lane) ----
    if (mode != 2) {
#pragma unroll
        for (int j = 0; j < 2; ++j) {
            float fr = exp2f(-(float)(j * 16 + lr) * (13.2877123795494f / 32.0f));
#pragma unroll
            for (int i = 0; i < 4; ++i) {
                const int row0 = bm + wA + i * 16 + quad * 4;
#pragma unroll
                for (int r = 0; r < 4; ++r) {
                    float s, c;
                    sincosf((float)(row0 + r) * fr, &s, &c);
                    float x1 = acc[i][j][r], x2 = acc[i][j + 2][r];
                    acc[i][j][r]     = x1 * c - x2 * s;
                    acc[i][j + 2][r] = x2 * c + x1 * s;
                }
            }
        }
    }

#pragma unroll
    for (int i = 0; i < 4; ++i) {
        const int row0 = bm + wA + i * 16 + quad * 4;
        if (mode == 0) {           // Q: bf16, pre-scaled by 1/8 (exact)
#pragma unroll
            for (int j = 0; j < 4; ++j) {
                int col = coff + j * 16 + lr;
#pragma unroll
                for (int r = 0; r < 4; ++r)
                    Qo[(size_t)(row0 + r) * DMODEL + col] = f2bf_rne(0.125f * acc[i][j][r]);
            }
        } else if (mode == 1) {    // K: bf16 natural [T][512]
#pragma unroll
            for (int j = 0; j < 4; ++j) {
                int col = coff + j * 16 + lr;
#pragma unroll
                for (int r = 0; r < 4; ++r)
                    Ko[(size_t)(row0 + r) * KVDIM + col] = f2bf_rne(acc[i][j][r]);
            }
        } else {                   // V: bf16 TRANSPOSED [512][T]
#pragma unroll
            for (int j = 0; j < 4; ++j) {
                int col = coff + j * 16 + lr;
                short4 pk;
                pk.x = (short)f2bf_rne(acc[i][j][0]);
                pk.y = (short)f2bf_rne(acc[i][j][1]);
                pk.z = (short)f2bf_rne(acc[i][j][2]);
                pk.w = (short)f2bf_rne(acc[i][j][3]);
                *(short4*)&Vo[(size_t)col * TLEN + row0] = pk;
            }
        }
    }
}

// ---------------------------------------------------------------------------
// MFMA flash attention, m=0 softmax (no running max: scores are O(5) << 88,
// softmax is shift-invariant so this is exact in fp32), deferred l-reduction.
// K/V/Q staged via global_load_lds into swizzled stride-64 LDS.
// ---------------------------------------------------------------------------
__global__ __launch_bounds__(256) void attn_mfma(const unsigned short* __restrict__ Qb,
                                                 const unsigned short* __restrict__ Kb,
                                                 const unsigned short* __restrict__ Vt,
                                                 unsigned short* __restrict__ Ab) {
    __shared__ short Qs[64][64];
    __shared__ short Ks[64][64];
    __shared__ short Vs[64][64];
    __shared__ short Ps[64][72];   // padded; C->A layout scatter target

    const int h = blockIdx.y, q0 = blockIdx.x * 64, kvh = h >> 2;
    const int tid = threadIdx.x;
    const int w = tid >> 6, lane = tid & 63;
    const int l15 = lane & 15, quad = lane >> 4;

    // staging lane map: row += lane>>3, phys chunk lane&7,
    // global chunk = (lane&7) ^ ((lane>>3)&7)
    const int sr  = lane >> 3;                    // 0..7
    const int sgc = ((lane & 7) ^ sr) * 8;        // swizzled chunk offset (shorts)

    {   // stage Q tile once (wave w: rows w*16 .. w*16+15)
        const unsigned short* qsrc = Qb + (size_t)(q0 + w * 16 + sr) * DMODEL + h * HDIM + sgc;
        GL16(qsrc,             &Qs[w * 16 + 0][0]);
        GL16(qsrc + 8 * DMODEL, &Qs[w * 16 + 8][0]);
    }

    floatx4 o[4];
#pragma unroll
    for (int j = 0; j < 4; ++j) o[j] = (floatx4)0.0f;
    float l_lane[4] = {0.0f, 0.0f, 0.0f, 0.0f};

    for (int c = 0; c < 9; ++c) {
        const int ch0 = q0 - WHALF + c * 64;
        if (ch0 < 0 || ch0 >= TLEN) continue;   // block-uniform

        __syncthreads();
        {
            const unsigned short* ksrc = Kb + (size_t)(ch0 + w * 16 + sr) * KVDIM + kvh * HDIM + sgc;
            const unsigned short* vsrc = Vt + (size_t)(kvh * HDIM + w * 16 + sr) * TLEN + ch0 + sgc;
            GL16(ksrc,             &Ks[w * 16 + 0][0]);
            GL16(ksrc + 8 * KVDIM, &Ks[w * 16 + 8][0]);
            GL16(vsrc,             &Vs[w * 16 + 0][0]);
            GL16(vsrc + 8 * TLEN,  &Vs[w * 16 + 8][0]);
        }
        __syncthreads();

        // ---- scores: S[16q x 64k] per wave, 8 MFMAs ----
        floatx4 sacc[4];
#pragma unroll
        for (int t = 0; t < 4; ++t) sacc[t] = (floatx4)0.0f;
#pragma unroll
        for (int s = 0; s < 2; ++s) {
            const int cs = ((s * 4 + quad) ^ (l15 & 7)) * 8;
            shortx8 aq = *(shortx8*)&Qs[w * 16 + l15][cs];
#pragma unroll
            for (int t = 0; t < 4; ++t) {
                shortx8 bk = *(shortx8*)&Ks[t * 16 + l15][cs];
                sacc[t] = __builtin_amdgcn_mfma_f32_16x16x32_bf16(aq, bk, sacc[t], 0, 0, 0);
            }
        }

        // ---- m=0 softmax: mask -> exp -> accumulate per-lane l, scatter P ----
#pragma unroll
        for (int r = 0; r < 4; ++r) {
            const int q = q0 + w * 16 + quad * 4 + r;
#pragma unroll
            for (int t = 0; t < 4; ++t) {
                const int k = ch0 + t * 16 + l15;
                bool valid = (k >= q - WHALF) && (k < q + WHALF);
                float p = valid ? __expf(sacc[t][r]) : 0.0f;
                l_lane[r] += p;
                Ps[w * 16 + quad * 4 + r][t * 16 + l15] = (short)f2bf_rne(p);
            }
        }
        __syncthreads();

        // ---- PV: O[16q x 64d] += P @ V, 8 MFMAs ----
#pragma unroll
        for (int ks = 0; ks < 2; ++ks) {
            const int cs = ((ks * 4 + quad) ^ (l15 & 7)) * 8;
            shortx8 ap = *(shortx8*)&Ps[w * 16 + l15][ks * 32 + quad * 8];
#pragma unroll
            for (int j = 0; j < 4; ++j) {
                shortx8 bv = *(shortx8*)&Vs[j * 16 + l15][cs];
                o[j] = __builtin_amdgcn_mfma_f32_16x16x32_bf16(ap, bv, o[j], 0, 0, 0);
            }
        }
    }

    // ---- epilogue: one l-reduction per row, divide, store bf16 ----
#pragma unroll
    for (int r = 0; r < 4; ++r) {
        float l = l_lane[r];
#pragma unroll
        for (int mb = 1; mb < 16; mb <<= 1)
            l += __shfl_xor(l, mb, 64);
        float inv = 1.0f / l;
        const int q = q0 + w * 16 + quad * 4 + r;
#pragma unroll
        for (int j = 0; j < 4; ++j)
            Ab[(size_t)q * DMODEL + h * HDIM + j * 16 + l15] = f2bf_rne(o[j][r] * inv);
    }
}

// ---------------------------------------------------------------------------
// Output projection, 256x64 tile, BK=128 (m97 geometry, wave 64x64).
// Grid (32, 8) = 256 blocks = 1/CU exactly. C fp32 = Ab @ Wob^T.
// ---------------------------------------------------------------------------
__global__ __launch_bounds__(256) void gemm_oproj(const unsigned short* __restrict__ Ab,
                                                  const unsigned short* __restrict__ Wob,
                                                  float* __restrict__ C) {
    __shared__ short Ah[256][128];
    __shared__ short Bh[64][128];

    const int bm = blockIdx.y * 256, bn = blockIdx.x * 64;
    const int tid = threadIdx.x;
    const int w = tid >> 6, lane = tid & 63;
    const int wA = w * 64, wB = w * 16;
    const int lr = lane & 15, quad = lane >> 4;
    const int r4 = lane >> 4;

    const unsigned short* Ag[4];
    const unsigned short* Bg[4];
#pragma unroll
    for (int gm = 0; gm < 4; ++gm) {
        const int cof = ((lane & 15) ^ r4 ^ (gm << 2)) * 8;
        Ag[gm] = Ab  + (size_t)(bm + wA + 4 * gm + r4) * DMODEL + cof;
        Bg[gm] = Wob + (size_t)(bn + wB + 4 * gm + r4) * DMODEL + cof;
    }

    floatx4 acc[4][4];
#pragma unroll
    for (int i = 0; i < 4; ++i)
#pragma unroll
        for (int j = 0; j < 4; ++j) acc[i][j] = (floatx4)0.0f;

    for (int k0 = 0; k0 < DMODEL; k0 += 128) {
        __syncthreads();
#pragma unroll
        for (int q = 0; q < 4; ++q)
#pragma unroll
            for (int gm = 0; gm < 4; ++gm)
                GL16(Ag[gm] + (size_t)(16 * q) * DMODEL + k0, &Ah[wA + 16 * q + 4 * gm][0]);
#pragma unroll
        for (int gm = 0; gm < 4; ++gm)
            GL16(Bg[gm] + k0, &Bh[wB + 4 * gm][0]);
        __syncthreads();

#pragma unroll
        for (int s = 0; s < 4; ++s) {
            const int cs = ((s * 4 + quad) ^ lr) * 8;
            shortx8 af[4], bf[4];
#pragma unroll
            for (int i = 0; i < 4; ++i) af[i] = *(shortx8*)&Ah[wA + i * 16 + lr][cs];
#pragma unroll
            for (int j = 0; j < 4; ++j) bf[j] = *(shortx8*)&Bh[j * 16 + lr][cs];
#pragma unroll
            for (int i = 0; i < 4; ++i)
#pragma unroll
                for (int j = 0; j < 4; ++j)
                    acc[i][j] = __builtin_amdgcn_mfma_f32_16x16x32_bf16(af[i], bf[j], acc[i][j], 0, 0, 0);
        }
    }

#pragma unroll
    for (int i = 0; i < 4; ++i) {
        const int row0 = bm + wA + i * 16 + quad * 4;
#pragma unroll
        for (int j = 0; j < 4; ++j) {
            int col = bn + j * 16 + lr;
#pragma unroll
            for (int r = 0; r < 4; ++r)
                C[(size_t)(row0 + r) * DMODEL + col] = acc[i][j][r];
        }
    }
}

// ---------------------------------------------------------------------------
extern "C" void kernel_launch(void* const* d_in, const int* in_sizes, int n_in,
                              void* d_out, int out_size, void* d_ws, size_t ws_size,
                              hipStream_t stream) {
    const float* hs = (const float*)d_in[0];
    const float* Wq = (const float*)d_in[1];
    const float* Wk = (const float*)d_in[2];
    const float* Wv = (const float*)d_in[3];
    const float* Wo = (const float*)d_in[4];
    float* out = (float*)d_out;

    // workspace: ~42 MB bf16. hsb buffer reused as Ab.
    unsigned short* Qb   = (unsigned short*)d_ws;            // [T][2048] rotated, /8
    unsigned short* Kb   = Qb + (size_t)TLEN * DMODEL;       // [T][512]  rotated
    unsigned short* Vt   = Kb + (size_t)TLEN * KVDIM;        // [512][T]  transposed
    unsigned short* hsAb = Vt + (size_t)KVDIM * TLEN;        // [T][2048] hs bf16, then attn out
    unsigned short* Wcat = hsAb + (size_t)TLEN * DMODEL;     // [3072][2048] {Wq;Wk;Wv} bf16
    unsigned short* Wob  = Wcat + (size_t)3072 * DMODEL;     // [2048][2048] Wo bf16

    dim3 blk(256);

    convert_inputs<<<1792, blk, 0, stream>>>(hs, Wq, Wk, Wv, Wo, hsAb, Wcat, Wob);

    gemm_qkv<<<dim3(48, TLEN / 256), blk, 0, stream>>>(hsAb, Wcat, Qb, Kb, Vt);

    attn_mfma<<<dim3(TLEN / 64, NHEADS), blk, 0, stream>>>(Qb, Kb, Vt, hsAb);

    gemm_oproj<<<dim3(DMODEL / 64, TLEN / 256), blk, 0, stream>>>(hsAb, Wob, out);
}

// Round 3
// 185.537 us; speedup vs baseline: 1.2516x; 1.2516x over previous
//
#include <hip/hip_runtime.h>
#include <math.h>

#define TLEN 2048
#define DMODEL 2048
#define NHEADS 32
#define NKV 8
#define HDIM 64
#define KVDIM 512      // NKV * HDIM
#define WHALF 256      // WINDOW/2

typedef short shortx8 __attribute__((ext_vector_type(8)));
typedef float floatx4 __attribute__((ext_vector_type(4)));
typedef unsigned int uint32;

__device__ __forceinline__ unsigned short f2bf_rne(float x) {
    union { float f; uint32 u; } v; v.f = x;
    uint32 r = v.u + 0x7FFFu + ((v.u >> 16) & 1u);
    return (unsigned short)(r >> 16);
}

// async global->LDS, 16B per lane; LDS dst = wave-uniform base + lane*16
#define GL16(g, l)                                                              \
    __builtin_amdgcn_global_load_lds(                                           \
        (const __attribute__((address_space(1))) unsigned int*)(g),             \
        (__attribute__((address_space(3))) unsigned int*)(l), 16, 0, 0)

// ---------------------------------------------------------------------------
// One-time fp32 -> bf16: hs->hsb, {Wq,Wk,Wv}->Wcat[3072][2048], Wo->Wob.
// ---------------------------------------------------------------------------
__global__ __launch_bounds__(256) void convert_inputs(const float* __restrict__ hs,
                                                      const float* __restrict__ Wq,
                                                      const float* __restrict__ Wk,
                                                      const float* __restrict__ Wv,
                                                      const float* __restrict__ Wo,
                                                      unsigned short* __restrict__ hsb,
                                                      unsigned short* __restrict__ Wcat,
                                                      unsigned short* __restrict__ Wob) {
    int b = blockIdx.x;
    const float* src; unsigned short* dst;
    if (b < 512)       { src = hs; dst = hsb; }
    else if (b < 1024) { src = Wq; dst = Wcat;                           b -= 512; }
    else if (b < 1152) { src = Wk; dst = Wcat + (size_t)2048 * DMODEL;   b -= 1024; }
    else if (b < 1280) { src = Wv; dst = Wcat + (size_t)2560 * DMODEL;   b -= 1152; }
    else               { src = Wo; dst = Wob;                            b -= 1280; }
    size_t base = (size_t)b * 8192 + threadIdx.x * 4;
#pragma unroll
    for (int it = 0; it < 8; ++it) {
        size_t off = base + (size_t)it * 1024;
        float4 v = *(const float4*)(src + off);
        short4 p;
        p.x = (short)f2bf_rne(v.x); p.y = (short)f2bf_rne(v.y);
        p.z = (short)f2bf_rne(v.z); p.w = (short)f2bf_rne(v.w);
        *(short4*)(dst + off) = p;
    }
}

// ---------------------------------------------------------------------------
// Fused Q/K/V projection, pure bf16, 128x64 tile, BK=128 (2 barriers / 128 k).
// Grid (48, 16) = 768 blocks = 3 blocks/CU (LDS 48 KB).  Wave tile 32x64.
// LDS rows = 256B = 16 chunks of 16B; phys chunk = logical ^ (row&15)
// (4-bit XOR -> conflict-free ds_read_b128, proven round 2).
// ---------------------------------------------------------------------------
__global__ __launch_bounds__(256) void gemm_qkv(const unsigned short* __restrict__ hsb,
                                                const unsigned short* __restrict__ Wcat,
                                                unsigned short* __restrict__ Qo,
                                                unsigned short* __restrict__ Ko,
                                                unsigned short* __restrict__ Vo) {
    __shared__ short Ah[128][128];
    __shared__ short Bh[64][128];

    const int bnx = blockIdx.x;
    int mode, coff;   // 0=Q (32 tiles), 1=K (8), 2=V (8)
    if (bnx < 32)      { mode = 0; coff = bnx * 64; }
    else if (bnx < 40) { mode = 1; coff = (bnx - 32) * 64; }
    else               { mode = 2; coff = (bnx - 40) * 64; }
    const unsigned short* Bbase = Wcat + (size_t)bnx * 64 * DMODEL;

    const int bm = blockIdx.y * 128;
    const int tid = threadIdx.x;
    const int w = tid >> 6, lane = tid & 63;
    const int wA = w * 32, wB = w * 16;
    const int lr = lane & 15, quad = lane >> 4;
    const int r4 = lane >> 4;

    // staging: each GL16 covers rows base + 4g + r4; row&15 = 4*(g&3) + r4.
    // source logical chunk = phys(lane&15) ^ r4 ^ ((g&3)<<2)
    const unsigned short* Ag[4];
    const unsigned short* Bg[4];
#pragma unroll
    for (int gm = 0; gm < 4; ++gm) {
        const int cof = ((lane & 15) ^ r4 ^ (gm << 2)) * 8;
        Ag[gm] = hsb   + (size_t)(bm + wA + 4 * gm + r4) * DMODEL + cof;
        Bg[gm] = Bbase + (size_t)(wB + 4 * gm + r4) * DMODEL + cof;
    }

    floatx4 acc[2][4];
#pragma unroll
    for (int i = 0; i < 2; ++i)
#pragma unroll
        for (int j = 0; j < 4; ++j) acc[i][j] = (floatx4)0.0f;

    for (int k0 = 0; k0 < DMODEL; k0 += 128) {
        __syncthreads();
#pragma unroll
        for (int q = 0; q < 2; ++q)
#pragma unroll
            for (int gm = 0; gm < 4; ++gm)
                GL16(Ag[gm] + (size_t)(16 * q) * DMODEL + k0, &Ah[wA + 16 * q + 4 * gm][0]);
#pragma unroll
        for (int gm = 0; gm < 4; ++gm)
            GL16(Bg[gm] + k0, &Bh[wB + 4 * gm][0]);
        __syncthreads();

#pragma unroll
        for (int s = 0; s < 4; ++s) {
            const int cs = ((s * 4 + quad) ^ lr) * 8;
            shortx8 a0 = *(shortx8*)&Ah[wA + lr][cs];
            shortx8 a1 = *(shortx8*)&Ah[wA + 16 + lr][cs];
            shortx8 bf[4];
#pragma unroll
            for (int j = 0; j < 4; ++j) bf[j] = *(shortx8*)&Bh[j * 16 + lr][cs];
#pragma unroll
            for (int j = 0; j < 4; ++j)
                acc[0][j] = __builtin_amdgcn_mfma_f32_16x16x32_bf16(a0, bf[j], acc[0][j], 0, 0, 0);
#pragma unroll
            for (int j = 0; j < 4; ++j)
                acc[1][j] = __builtin_amdgcn_mfma_f32_16x16x32_bf16(a1, bf[j], acc[1][j], 0, 0, 0);
        }
    }

    // ---- fused RoPE (pair (d,d+32) = acc[i][j], acc[i][j+2], same lane) ----
    if (mode != 2) {
#pragma unroll
        for (int j = 0; j < 2; ++j) {
            float fr = exp2f(-(float)(j * 16 + lr) * (13.2877123795494f / 32.0f));
#pragma unroll
            for (int i = 0; i < 2; ++i) {
                const int row0 = bm + wA + i * 16 + quad * 4;
#pragma unroll
                for (int r = 0; r < 4; ++r) {
                    float s, c;
                    sincosf((float)(row0 + r) * fr, &s, &c);
                    float x1 = acc[i][j][r], x2 = acc[i][j + 2][r];
                    acc[i][j][r]     = x1 * c - x2 * s;
                    acc[i][j + 2][r] = x2 * c + x1 * s;
                }
            }
        }
    }

#pragma unroll
    for (int i = 0; i < 2; ++i) {
        const int row0 = bm + wA + i * 16 + quad * 4;
        if (mode == 0) {           // Q: bf16, pre-scaled by 1/8 (exact)
#pragma unroll
            for (int j = 0; j < 4; ++j) {
                int col = coff + j * 16 + lr;
#pragma unroll
                for (int r = 0; r < 4; ++r)
                    Qo[(size_t)(row0 + r) * DMODEL + col] = f2bf_rne(0.125f * acc[i][j][r]);
            }
        } else if (mode == 1) {    // K: bf16 natural [T][512]
#pragma unroll
            for (int j = 0; j < 4; ++j) {
                int col = coff + j * 16 + lr;
#pragma unroll
                for (int r = 0; r < 4; ++r)
                    Ko[(size_t)(row0 + r) * KVDIM + col] = f2bf_rne(acc[i][j][r]);
            }
        } else {                   // V: bf16 TRANSPOSED [512][T]
#pragma unroll
            for (int j = 0; j < 4; ++j) {
                int col = coff + j * 16 + lr;
                short4 pk;
                pk.x = (short)f2bf_rne(acc[i][j][0]);
                pk.y = (short)f2bf_rne(acc[i][j][1]);
                pk.z = (short)f2bf_rne(acc[i][j][2]);
                pk.w = (short)f2bf_rne(acc[i][j][3]);
                *(short4*)&Vo[(size_t)col * TLEN + row0] = pk;
            }
        }
    }
}

// ---------------------------------------------------------------------------
// MFMA flash attention, m=0 softmax (no running max: scores are O(5) << 88,
// softmax is shift-invariant so this is exact in fp32), deferred l-reduction.
// K/V/Q staged via global_load_lds into swizzled stride-64 LDS.
// ---------------------------------------------------------------------------
__global__ __launch_bounds__(256) void attn_mfma(const unsigned short* __restrict__ Qb,
                                                 const unsigned short* __restrict__ Kb,
                                                 const unsigned short* __restrict__ Vt,
                                                 unsigned short* __restrict__ Ab) {
    __shared__ short Qs[64][64];
    __shared__ short Ks[64][64];
    __shared__ short Vs[64][64];
    __shared__ short Ps[64][72];   // padded; C->A layout scatter target

    const int h = blockIdx.y, q0 = blockIdx.x * 64, kvh = h >> 2;
    const int tid = threadIdx.x;
    const int w = tid >> 6, lane = tid & 63;
    const int l15 = lane & 15, quad = lane >> 4;

    // staging lane map: row += lane>>3, phys chunk lane&7,
    // global chunk = (lane&7) ^ ((lane>>3)&7)
    const int sr  = lane >> 3;                    // 0..7
    const int sgc = ((lane & 7) ^ sr) * 8;        // swizzled chunk offset (shorts)

    {   // stage Q tile once (wave w: rows w*16 .. w*16+15)
        const unsigned short* qsrc = Qb + (size_t)(q0 + w * 16 + sr) * DMODEL + h * HDIM + sgc;
        GL16(qsrc,             &Qs[w * 16 + 0][0]);
        GL16(qsrc + 8 * DMODEL, &Qs[w * 16 + 8][0]);
    }

    floatx4 o[4];
#pragma unroll
    for (int j = 0; j < 4; ++j) o[j] = (floatx4)0.0f;
    float l_lane[4] = {0.0f, 0.0f, 0.0f, 0.0f};

    for (int c = 0; c < 9; ++c) {
        const int ch0 = q0 - WHALF + c * 64;
        if (ch0 < 0 || ch0 >= TLEN) continue;   // block-uniform

        __syncthreads();
        {
            const unsigned short* ksrc = Kb + (size_t)(ch0 + w * 16 + sr) * KVDIM + kvh * HDIM + sgc;
            const unsigned short* vsrc = Vt + (size_t)(kvh * HDIM + w * 16 + sr) * TLEN + ch0 + sgc;
            GL16(ksrc,             &Ks[w * 16 + 0][0]);
            GL16(ksrc + 8 * KVDIM, &Ks[w * 16 + 8][0]);
            GL16(vsrc,             &Vs[w * 16 + 0][0]);
            GL16(vsrc + 8 * TLEN,  &Vs[w * 16 + 8][0]);
        }
        __syncthreads();

        // ---- scores: S[16q x 64k] per wave, 8 MFMAs ----
        floatx4 sacc[4];
#pragma unroll
        for (int t = 0; t < 4; ++t) sacc[t] = (floatx4)0.0f;
#pragma unroll
        for (int s = 0; s < 2; ++s) {
            const int cs = ((s * 4 + quad) ^ (l15 & 7)) * 8;
            shortx8 aq = *(shortx8*)&Qs[w * 16 + l15][cs];
#pragma unroll
            for (int t = 0; t < 4; ++t) {
                shortx8 bk = *(shortx8*)&Ks[t * 16 + l15][cs];
                sacc[t] = __builtin_amdgcn_mfma_f32_16x16x32_bf16(aq, bk, sacc[t], 0, 0, 0);
            }
        }

        // ---- m=0 softmax: mask -> exp -> accumulate per-lane l, scatter P ----
#pragma unroll
        for (int r = 0; r < 4; ++r) {
            const int q = q0 + w * 16 + quad * 4 + r;
#pragma unroll
            for (int t = 0; t < 4; ++t) {
                const int k = ch0 + t * 16 + l15;
                bool valid = (k >= q - WHALF) && (k < q + WHALF);
                float p = valid ? __expf(sacc[t][r]) : 0.0f;
                l_lane[r] += p;
                Ps[w * 16 + quad * 4 + r][t * 16 + l15] = (short)f2bf_rne(p);
            }
        }
        __syncthreads();

        // ---- PV: O[16q x 64d] += P @ V, 8 MFMAs ----
#pragma unroll
        for (int ks = 0; ks < 2; ++ks) {
            const int cs = ((ks * 4 + quad) ^ (l15 & 7)) * 8;
            shortx8 ap = *(shortx8*)&Ps[w * 16 + l15][ks * 32 + quad * 8];
#pragma unroll
            for (int j = 0; j < 4; ++j) {
                shortx8 bv = *(shortx8*)&Vs[j * 16 + l15][cs];
                o[j] = __builtin_amdgcn_mfma_f32_16x16x32_bf16(ap, bv, o[j], 0, 0, 0);
            }
        }
    }

    // ---- epilogue: one l-reduction per row, divide, store bf16 ----
#pragma unroll
    for (int r = 0; r < 4; ++r) {
        float l = l_lane[r];
#pragma unroll
        for (int mb = 1; mb < 16; mb <<= 1)
            l += __shfl_xor(l, mb, 64);
        float inv = 1.0f / l;
        const int q = q0 + w * 16 + quad * 4 + r;
#pragma unroll
        for (int j = 0; j < 4; ++j)
            Ab[(size_t)q * DMODEL + h * HDIM + j * 16 + l15] = f2bf_rne(o[j][r] * inv);
    }
}

// ---------------------------------------------------------------------------
// Output projection, 128x64 tile, BK=128, 4-bit XOR swizzle.
// Grid (32, 16) = 512 blocks. C fp32 = Ab @ Wob^T.
// ---------------------------------------------------------------------------
__global__ __launch_bounds__(256) void gemm_oproj(const unsigned short* __restrict__ Ab,
                                                  const unsigned short* __restrict__ Wob,
                                                  float* __restrict__ C) {
    __shared__ short Ah[128][128];
    __shared__ short Bh[64][128];

    const int bm = blockIdx.y * 128, bn = blockIdx.x * 64;
    const int tid = threadIdx.x;
    const int w = tid >> 6, lane = tid & 63;
    const int wA = w * 32, wB = w * 16;
    const int lr = lane & 15, quad = lane >> 4;
    const int r4 = lane >> 4;

    const unsigned short* Ag[4];
    const unsigned short* Bg[4];
#pragma unroll
    for (int gm = 0; gm < 4; ++gm) {
        const int cof = ((lane & 15) ^ r4 ^ (gm << 2)) * 8;
        Ag[gm] = Ab  + (size_t)(bm + wA + 4 * gm + r4) * DMODEL + cof;
        Bg[gm] = Wob + (size_t)(bn + wB + 4 * gm + r4) * DMODEL + cof;
    }

    floatx4 acc[2][4];
#pragma unroll
    for (int i = 0; i < 2; ++i)
#pragma unroll
        for (int j = 0; j < 4; ++j) acc[i][j] = (floatx4)0.0f;

    for (int k0 = 0; k0 < DMODEL; k0 += 128) {
        __syncthreads();
#pragma unroll
        for (int q = 0; q < 2; ++q)
#pragma unroll
            for (int gm = 0; gm < 4; ++gm)
                GL16(Ag[gm] + (size_t)(16 * q) * DMODEL + k0, &Ah[wA + 16 * q + 4 * gm][0]);
#pragma unroll
        for (int gm = 0; gm < 4; ++gm)
            GL16(Bg[gm] + k0, &Bh[wB + 4 * gm][0]);
        __syncthreads();

#pragma unroll
        for (int s = 0; s < 4; ++s) {
            const int cs = ((s * 4 + quad) ^ lr) * 8;
            shortx8 a0 = *(shortx8*)&Ah[wA + lr][cs];
            shortx8 a1 = *(shortx8*)&Ah[wA + 16 + lr][cs];
            shortx8 bf[4];
#pragma unroll
            for (int j = 0; j < 4; ++j) bf[j] = *(shortx8*)&Bh[j * 16 + lr][cs];
#pragma unroll
            for (int j = 0; j < 4; ++j)
                acc[0][j] = __builtin_amdgcn_mfma_f32_16x16x32_bf16(a0, bf[j], acc[0][j], 0, 0, 0);
#pragma unroll
            for (int j = 0; j < 4; ++j)
                acc[1][j] = __builtin_amdgcn_mfma_f32_16x16x32_bf16(a1, bf[j], acc[1][j], 0, 0, 0);
        }
    }

#pragma unroll
    for (int i = 0; i < 2; ++i) {
        const int row0 = bm + wA + i * 16 + quad * 4;
#pragma unroll
        for (int j = 0; j < 4; ++j) {
            int col = bn + j * 16 + lr;
#pragma unroll
            for (int r = 0; r < 4; ++r)
                C[(size_t)(row0 + r) * DMODEL + col] = acc[i][j][r];
        }
    }
}

// ---------------------------------------------------------------------------
extern "C" void kernel_launch(void* const* d_in, const int* in_sizes, int n_in,
                              void* d_out, int out_size, void* d_ws, size_t ws_size,
                              hipStream_t stream) {
    const float* hs = (const float*)d_in[0];
    const float* Wq = (const float*)d_in[1];
    const float* Wk = (const float*)d_in[2];
    const float* Wv = (const float*)d_in[3];
    const float* Wo = (const float*)d_in[4];
    float* out = (float*)d_out;

    // workspace: ~42 MB bf16. hsb buffer reused as Ab.
    unsigned short* Qb   = (unsigned short*)d_ws;            // [T][2048] rotated, /8
    unsigned short* Kb   = Qb + (size_t)TLEN * DMODEL;       // [T][512]  rotated
    unsigned short* Vt   = Kb + (size_t)TLEN * KVDIM;        // [512][T]  transposed
    unsigned short* hsAb = Vt + (size_t)KVDIM * TLEN;        // [T][2048] hs bf16, then attn out
    unsigned short* Wcat = hsAb + (size_t)TLEN * DMODEL;     // [3072][2048] {Wq;Wk;Wv} bf16
    unsigned short* Wob  = Wcat + (size_t)3072 * DMODEL;     // [2048][2048] Wo bf16

    dim3 blk(256);

    convert_inputs<<<1792, blk, 0, stream>>>(hs, Wq, Wk, Wv, Wo, hsAb, Wcat, Wob);

    gemm_qkv<<<dim3(48, TLEN / 128), blk, 0, stream>>>(hsAb, Wcat, Qb, Kb, Vt);

    attn_mfma<<<dim3(TLEN / 64, NHEADS), blk, 0, stream>>>(Qb, Kb, Vt, hsAb);

    gemm_oproj<<<dim3(DMODEL / 64, TLEN / 128), blk, 0, stream>>>(hsAb, Wob, out);
}

// Round 4
// 183.244 us; speedup vs baseline: 1.2673x; 1.0125x over previous
//
#include <hip/hip_runtime.h>
#include <math.h>

#define TLEN 2048
#define DMODEL 2048
#define NHEADS 32
#define NKV 8
#define HDIM 64
#define KVDIM 512      // NKV * HDIM
#define WHALF 256      // WINDOW/2

typedef short shortx8 __attribute__((ext_vector_type(8)));
typedef float floatx4 __attribute__((ext_vector_type(4)));
typedef unsigned int uint32;

__device__ __forceinline__ unsigned short f2bf_rne(float x) {
    union { float f; uint32 u; } v; v.f = x;
    uint32 r = v.u + 0x7FFFu + ((v.u >> 16) & 1u);
    return (unsigned short)(r >> 16);
}

// async global->LDS, 16B per lane; LDS dst = wave-uniform base + lane*16
#define GL16(g, l)                                                              \
    __builtin_amdgcn_global_load_lds(                                           \
        (const __attribute__((address_space(1))) unsigned int*)(g),             \
        (__attribute__((address_space(3))) unsigned int*)(l), 16, 0, 0)

// ---------------------------------------------------------------------------
// One-time fp32 -> bf16: hs->hsb, {Wq,Wk,Wv}->Wcat[3072][2048], Wo->Wob.
// ---------------------------------------------------------------------------
__global__ __launch_bounds__(256) void convert_inputs(const float* __restrict__ hs,
                                                      const float* __restrict__ Wq,
                                                      const float* __restrict__ Wk,
                                                      const float* __restrict__ Wv,
                                                      const float* __restrict__ Wo,
                                                      unsigned short* __restrict__ hsb,
                                                      unsigned short* __restrict__ Wcat,
                                                      unsigned short* __restrict__ Wob) {
    int b = blockIdx.x;
    const float* src; unsigned short* dst;
    if (b < 512)       { src = hs; dst = hsb; }
    else if (b < 1024) { src = Wq; dst = Wcat;                           b -= 512; }
    else if (b < 1152) { src = Wk; dst = Wcat + (size_t)2048 * DMODEL;   b -= 1024; }
    else if (b < 1280) { src = Wv; dst = Wcat + (size_t)2560 * DMODEL;   b -= 1152; }
    else               { src = Wo; dst = Wob;                            b -= 1280; }
    size_t base = (size_t)b * 8192 + threadIdx.x * 4;
#pragma unroll
    for (int it = 0; it < 8; ++it) {
        size_t off = base + (size_t)it * 1024;
        float4 v = *(const float4*)(src + off);
        short4 p;
        p.x = (short)f2bf_rne(v.x); p.y = (short)f2bf_rne(v.y);
        p.z = (short)f2bf_rne(v.z); p.w = (short)f2bf_rne(v.w);
        *(short4*)(dst + off) = p;
    }
}

// ---------------------------------------------------------------------------
// Fused Q/K/V projection, pure bf16, 128x64 tile, BK=128 (2 barriers / 128 k).
// Grid (48, 16) = 768 blocks = 3 blocks/CU (LDS 48 KB).  Wave tile 32x64.
// LDS rows = 256B = 16 chunks of 16B; phys chunk = logical ^ (row&15)
// (4-bit XOR -> conflict-free ds_read_b128, proven round 2).
// ---------------------------------------------------------------------------
__global__ __launch_bounds__(256) void gemm_qkv(const unsigned short* __restrict__ hsb,
                                                const unsigned short* __restrict__ Wcat,
                                                unsigned short* __restrict__ Qo,
                                                unsigned short* __restrict__ Ko,
                                                unsigned short* __restrict__ Vo) {
    __shared__ short Ah[128][128];
    __shared__ short Bh[64][128];

    const int bnx = blockIdx.x;
    int mode, coff;   // 0=Q (32 tiles), 1=K (8), 2=V (8)
    if (bnx < 32)      { mode = 0; coff = bnx * 64; }
    else if (bnx < 40) { mode = 1; coff = (bnx - 32) * 64; }
    else               { mode = 2; coff = (bnx - 40) * 64; }
    const unsigned short* Bbase = Wcat + (size_t)bnx * 64 * DMODEL;

    const int bm = blockIdx.y * 128;
    const int tid = threadIdx.x;
    const int w = tid >> 6, lane = tid & 63;
    const int wA = w * 32, wB = w * 16;
    const int lr = lane & 15, quad = lane >> 4;
    const int r4 = lane >> 4;

    // staging: each GL16 covers rows base + 4g + r4; row&15 = 4*(g&3) + r4.
    // source logical chunk = phys(lane&15) ^ r4 ^ ((g&3)<<2)
    const unsigned short* Ag[4];
    const unsigned short* Bg[4];
#pragma unroll
    for (int gm = 0; gm < 4; ++gm) {
        const int cof = ((lane & 15) ^ r4 ^ (gm << 2)) * 8;
        Ag[gm] = hsb   + (size_t)(bm + wA + 4 * gm + r4) * DMODEL + cof;
        Bg[gm] = Bbase + (size_t)(wB + 4 * gm + r4) * DMODEL + cof;
    }

    floatx4 acc[2][4];
#pragma unroll
    for (int i = 0; i < 2; ++i)
#pragma unroll
        for (int j = 0; j < 4; ++j) acc[i][j] = (floatx4)0.0f;

    for (int k0 = 0; k0 < DMODEL; k0 += 128) {
        __syncthreads();
#pragma unroll
        for (int q = 0; q < 2; ++q)
#pragma unroll
            for (int gm = 0; gm < 4; ++gm)
                GL16(Ag[gm] + (size_t)(16 * q) * DMODEL + k0, &Ah[wA + 16 * q + 4 * gm][0]);
#pragma unroll
        for (int gm = 0; gm < 4; ++gm)
            GL16(Bg[gm] + k0, &Bh[wB + 4 * gm][0]);
        __syncthreads();

#pragma unroll
        for (int s = 0; s < 4; ++s) {
            const int cs = ((s * 4 + quad) ^ lr) * 8;
            shortx8 a0 = *(shortx8*)&Ah[wA + lr][cs];
            shortx8 a1 = *(shortx8*)&Ah[wA + 16 + lr][cs];
            shortx8 bf[4];
#pragma unroll
            for (int j = 0; j < 4; ++j) bf[j] = *(shortx8*)&Bh[j * 16 + lr][cs];
#pragma unroll
            for (int j = 0; j < 4; ++j)
                acc[0][j] = __builtin_amdgcn_mfma_f32_16x16x32_bf16(a0, bf[j], acc[0][j], 0, 0, 0);
#pragma unroll
            for (int j = 0; j < 4; ++j)
                acc[1][j] = __builtin_amdgcn_mfma_f32_16x16x32_bf16(a1, bf[j], acc[1][j], 0, 0, 0);
        }
    }

    // ---- fused RoPE (pair (d,d+32) = acc[i][j], acc[i][j+2], same lane) ----
    if (mode != 2) {
#pragma unroll
        for (int j = 0; j < 2; ++j) {
            float fr = exp2f(-(float)(j * 16 + lr) * (13.2877123795494f / 32.0f));
#pragma unroll
            for (int i = 0; i < 2; ++i) {
                const int row0 = bm + wA + i * 16 + quad * 4;
#pragma unroll
                for (int r = 0; r < 4; ++r) {
                    float s, c;
                    sincosf((float)(row0 + r) * fr, &s, &c);
                    float x1 = acc[i][j][r], x2 = acc[i][j + 2][r];
                    acc[i][j][r]     = x1 * c - x2 * s;
                    acc[i][j + 2][r] = x2 * c + x1 * s;
                }
            }
        }
    }

#pragma unroll
    for (int i = 0; i < 2; ++i) {
        const int row0 = bm + wA + i * 16 + quad * 4;
        if (mode == 0) {           // Q: bf16, pre-scaled by 1/8 (exact)
#pragma unroll
            for (int j = 0; j < 4; ++j) {
                int col = coff + j * 16 + lr;
#pragma unroll
                for (int r = 0; r < 4; ++r)
                    Qo[(size_t)(row0 + r) * DMODEL + col] = f2bf_rne(0.125f * acc[i][j][r]);
            }
        } else if (mode == 1) {    // K: bf16 natural [T][512]
#pragma unroll
            for (int j = 0; j < 4; ++j) {
                int col = coff + j * 16 + lr;
#pragma unroll
                for (int r = 0; r < 4; ++r)
                    Ko[(size_t)(row0 + r) * KVDIM + col] = f2bf_rne(acc[i][j][r]);
            }
        } else {                   // V: bf16 TRANSPOSED [512][T]
#pragma unroll
            for (int j = 0; j < 4; ++j) {
                int col = coff + j * 16 + lr;
                short4 pk;
                pk.x = (short)f2bf_rne(acc[i][j][0]);
                pk.y = (short)f2bf_rne(acc[i][j][1]);
                pk.z = (short)f2bf_rne(acc[i][j][2]);
                pk.w = (short)f2bf_rne(acc[i][j][3]);
                *(short4*)&Vo[(size_t)col * TLEN + row0] = pk;
            }
        }
    }
}

// ---------------------------------------------------------------------------
// MFMA flash attention, m=0 softmax (no running max: scores are O(5) << 88,
// softmax is shift-invariant so this is exact in fp32), deferred l-reduction.
// QBLK=128 (8 waves, 512 thr): K/V staged once per 128 q-rows (-37% stages),
// 2 barriers/chunk (Ps rows are wave-private -> no barrier before PV),
// wave-uniform window guard keeps compute work equal to the QBLK=64 version.
// ---------------------------------------------------------------------------
__global__ __launch_bounds__(512) void attn_mfma(const unsigned short* __restrict__ Qb,
                                                 const unsigned short* __restrict__ Kb,
                                                 const unsigned short* __restrict__ Vt,
                                                 unsigned short* __restrict__ Ab) {
    __shared__ short Qs[128][64];
    __shared__ short Ks[64][64];
    __shared__ short Vs[64][64];
    __shared__ short Ps[128][72];   // padded; C->A layout scatter target (wave-private rows)

    const int h = blockIdx.y, q0 = blockIdx.x * 128, kvh = h >> 2;
    const int tid = threadIdx.x;
    const int w = tid >> 6, lane = tid & 63;
    const int l15 = lane & 15, quad = lane >> 4;
    const int qw = q0 + w * 16;                   // this wave's first q-row

    // staging lane map: row += lane>>3, phys chunk lane&7,
    // global chunk = (lane&7) ^ ((lane>>3)&7)
    const int sr  = lane >> 3;                    // 0..7
    const int sgc = ((lane & 7) ^ sr) * 8;        // swizzled chunk offset (shorts)

    {   // stage Q tile once (wave w: rows w*16 .. w*16+15)
        const unsigned short* qsrc = Qb + (size_t)(qw + sr) * DMODEL + h * HDIM + sgc;
        GL16(qsrc,              &Qs[w * 16 + 0][0]);
        GL16(qsrc + 8 * DMODEL, &Qs[w * 16 + 8][0]);
    }

    floatx4 o[4];
#pragma unroll
    for (int j = 0; j < 4; ++j) o[j] = (floatx4)0.0f;
    float l_lane[4] = {0.0f, 0.0f, 0.0f, 0.0f};

    for (int c = 0; c < 10; ++c) {
        const int ch0 = q0 - WHALF + c * 64;
        if (ch0 < 0 || ch0 >= TLEN) continue;   // block-uniform

        __syncthreads();
        {   // 8 waves: wave w stages K rows ch0+w*8.. and V (d-)rows w*8..
            const unsigned short* ksrc = Kb + (size_t)(ch0 + w * 8 + sr) * KVDIM + kvh * HDIM + sgc;
            const unsigned short* vsrc = Vt + (size_t)(kvh * HDIM + w * 8 + sr) * TLEN + ch0 + sgc;
            GL16(ksrc, &Ks[w * 8][0]);
            GL16(vsrc, &Vs[w * 8][0]);
        }
        __syncthreads();

        // wave-uniform: does this chunk intersect any of this wave's windows?
        // rows [qw, qw+15] -> k union [qw-256, qw+270]; chunk [ch0, ch0+63]
        if (ch0 >= qw - 319 && ch0 <= qw + 270) {
            // ---- scores: S[16q x 64k] per wave, 8 MFMAs ----
            floatx4 sacc[4];
#pragma unroll
            for (int t = 0; t < 4; ++t) sacc[t] = (floatx4)0.0f;
#pragma unroll
            for (int s = 0; s < 2; ++s) {
                const int cs = ((s * 4 + quad) ^ (l15 & 7)) * 8;
                shortx8 aq = *(shortx8*)&Qs[w * 16 + l15][cs];
#pragma unroll
                for (int t = 0; t < 4; ++t) {
                    shortx8 bk = *(shortx8*)&Ks[t * 16 + l15][cs];
                    sacc[t] = __builtin_amdgcn_mfma_f32_16x16x32_bf16(aq, bk, sacc[t], 0, 0, 0);
                }
            }

            // ---- m=0 softmax: mask -> exp -> accumulate per-lane l, scatter P ----
#pragma unroll
            for (int r = 0; r < 4; ++r) {
                const int q = qw + quad * 4 + r;
#pragma unroll
                for (int t = 0; t < 4; ++t) {
                    const int k = ch0 + t * 16 + l15;
                    bool valid = (k >= q - WHALF) && (k < q + WHALF);
                    float p = valid ? __expf(sacc[t][r]) : 0.0f;
                    l_lane[r] += p;
                    Ps[w * 16 + quad * 4 + r][t * 16 + l15] = (short)f2bf_rne(p);
                }
            }

            // ---- PV: O[16q x 64d] += P @ V, 8 MFMAs (Ps rows wave-private,
            // within-wave lgkmcnt orders write->read; no barrier needed) ----
#pragma unroll
            for (int ks = 0; ks < 2; ++ks) {
                const int cs = ((ks * 4 + quad) ^ (l15 & 7)) * 8;
                shortx8 ap = *(shortx8*)&Ps[w * 16 + l15][ks * 32 + quad * 8];
#pragma unroll
                for (int j = 0; j < 4; ++j) {
                    shortx8 bv = *(shortx8*)&Vs[j * 16 + l15][cs];
                    o[j] = __builtin_amdgcn_mfma_f32_16x16x32_bf16(ap, bv, o[j], 0, 0, 0);
                }
            }
        }
    }

    // ---- epilogue: one l-reduction per row, divide, store bf16 ----
#pragma unroll
    for (int r = 0; r < 4; ++r) {
        float l = l_lane[r];
#pragma unroll
        for (int mb = 1; mb < 16; mb <<= 1)
            l += __shfl_xor(l, mb, 64);
        float inv = 1.0f / l;
        const int q = qw + quad * 4 + r;
#pragma unroll
        for (int j = 0; j < 4; ++j)
            Ab[(size_t)q * DMODEL + h * HDIM + j * 16 + l15] = f2bf_rne(o[j][r] * inv);
    }
}

// ---------------------------------------------------------------------------
// Output projection, 128x64 tile, BK=128, 4-bit XOR swizzle.
// Grid (32, 16) = 512 blocks. C fp32 = Ab @ Wob^T.
// ---------------------------------------------------------------------------
__global__ __launch_bounds__(256) void gemm_oproj(const unsigned short* __restrict__ Ab,
                                                  const unsigned short* __restrict__ Wob,
                                                  float* __restrict__ C) {
    __shared__ short Ah[128][128];
    __shared__ short Bh[64][128];

    const int bm = blockIdx.y * 128, bn = blockIdx.x * 64;
    const int tid = threadIdx.x;
    const int w = tid >> 6, lane = tid & 63;
    const int wA = w * 32, wB = w * 16;
    const int lr = lane & 15, quad = lane >> 4;
    const int r4 = lane >> 4;

    const unsigned short* Ag[4];
    const unsigned short* Bg[4];
#pragma unroll
    for (int gm = 0; gm < 4; ++gm) {
        const int cof = ((lane & 15) ^ r4 ^ (gm << 2)) * 8;
        Ag[gm] = Ab  + (size_t)(bm + wA + 4 * gm + r4) * DMODEL + cof;
        Bg[gm] = Wob + (size_t)(bn + wB + 4 * gm + r4) * DMODEL + cof;
    }

    floatx4 acc[2][4];
#pragma unroll
    for (int i = 0; i < 2; ++i)
#pragma unroll
        for (int j = 0; j < 4; ++j) acc[i][j] = (floatx4)0.0f;

    for (int k0 = 0; k0 < DMODEL; k0 += 128) {
        __syncthreads();
#pragma unroll
        for (int q = 0; q < 2; ++q)
#pragma unroll
            for (int gm = 0; gm < 4; ++gm)
                GL16(Ag[gm] + (size_t)(16 * q) * DMODEL + k0, &Ah[wA + 16 * q + 4 * gm][0]);
#pragma unroll
        for (int gm = 0; gm < 4; ++gm)
            GL16(Bg[gm] + k0, &Bh[wB + 4 * gm][0]);
        __syncthreads();

#pragma unroll
        for (int s = 0; s < 4; ++s) {
            const int cs = ((s * 4 + quad) ^ lr) * 8;
            shortx8 a0 = *(shortx8*)&Ah[wA + lr][cs];
            shortx8 a1 = *(shortx8*)&Ah[wA + 16 + lr][cs];
            shortx8 bf[4];
#pragma unroll
            for (int j = 0; j < 4; ++j) bf[j] = *(shortx8*)&Bh[j * 16 + lr][cs];
#pragma unroll
            for (int j = 0; j < 4; ++j)
                acc[0][j] = __builtin_amdgcn_mfma_f32_16x16x32_bf16(a0, bf[j], acc[0][j], 0, 0, 0);
#pragma unroll
            for (int j = 0; j < 4; ++j)
                acc[1][j] = __builtin_amdgcn_mfma_f32_16x16x32_bf16(a1, bf[j], acc[1][j], 0, 0, 0);
        }
    }

#pragma unroll
    for (int i = 0; i < 2; ++i) {
        const int row0 = bm + wA + i * 16 + quad * 4;
#pragma unroll
        for (int j = 0; j < 4; ++j) {
            int col = bn + j * 16 + lr;
#pragma unroll
            for (int r = 0; r < 4; ++r)
                C[(size_t)(row0 + r) * DMODEL + col] = acc[i][j][r];
        }
    }
}

// ---------------------------------------------------------------------------
extern "C" void kernel_launch(void* const* d_in, const int* in_sizes, int n_in,
                              void* d_out, int out_size, void* d_ws, size_t ws_size,
                              hipStream_t stream) {
    const float* hs = (const float*)d_in[0];
    const float* Wq = (const float*)d_in[1];
    const float* Wk = (const float*)d_in[2];
    const float* Wv = (const float*)d_in[3];
    const float* Wo = (const float*)d_in[4];
    float* out = (float*)d_out;

    // workspace: ~42 MB bf16. hsb buffer reused as Ab.
    unsigned short* Qb   = (unsigned short*)d_ws;            // [T][2048] rotated, /8
    unsigned short* Kb   = Qb + (size_t)TLEN * DMODEL;       // [T][512]  rotated
    unsigned short* Vt   = Kb + (size_t)TLEN * KVDIM;        // [512][T]  transposed
    unsigned short* hsAb = Vt + (size_t)KVDIM * TLEN;        // [T][2048] hs bf16, then attn out
    unsigned short* Wcat = hsAb + (size_t)TLEN * DMODEL;     // [3072][2048] {Wq;Wk;Wv} bf16
    unsigned short* Wob  = Wcat + (size_t)3072 * DMODEL;     // [2048][2048] Wo bf16

    dim3 blk(256);

    convert_inputs<<<1792, blk, 0, stream>>>(hs, Wq, Wk, Wv, Wo, hsAb, Wcat, Wob);

    gemm_qkv<<<dim3(48, TLEN / 128), blk, 0, stream>>>(hsAb, Wcat, Qb, Kb, Vt);

    attn_mfma<<<dim3(TLEN / 128, NHEADS), dim3(512), 0, stream>>>(Qb, Kb, Vt, hsAb);

    gemm_oproj<<<dim3(DMODEL / 64, TLEN / 128), blk, 0, stream>>>(hsAb, Wob, out);
}

// Round 5
// 181.178 us; speedup vs baseline: 1.2817x; 1.0114x over previous
//
#include <hip/hip_runtime.h>
#include <math.h>

#define TLEN 2048
#define DMODEL 2048
#define NHEADS 32
#define NKV 8
#define HDIM 64
#define KVDIM 512      // NKV * HDIM
#define WHALF 256      // WINDOW/2

typedef short shortx8 __attribute__((ext_vector_type(8)));
typedef float floatx4 __attribute__((ext_vector_type(4)));
typedef unsigned int uint32;

__device__ __forceinline__ unsigned short f2bf_rne(float x) {
    union { float f; uint32 u; } v; v.f = x;
    uint32 r = v.u + 0x7FFFu + ((v.u >> 16) & 1u);
    return (unsigned short)(r >> 16);
}

// async global->LDS, 16B per lane; LDS dst = wave-uniform base + lane*16
#define GL16(g, l)                                                              \
    __builtin_amdgcn_global_load_lds(                                           \
        (const __attribute__((address_space(1))) unsigned int*)(g),             \
        (__attribute__((address_space(3))) unsigned int*)(l), 16, 0, 0)

// ---------------------------------------------------------------------------
// One-time fp32 -> bf16: hs->hsb, {Wq,Wk,Wv}->Wcat[3072][2048], Wo->Wob.
// ---------------------------------------------------------------------------
__global__ __launch_bounds__(256) void convert_inputs(const float* __restrict__ hs,
                                                      const float* __restrict__ Wq,
                                                      const float* __restrict__ Wk,
                                                      const float* __restrict__ Wv,
                                                      const float* __restrict__ Wo,
                                                      unsigned short* __restrict__ hsb,
                                                      unsigned short* __restrict__ Wcat,
                                                      unsigned short* __restrict__ Wob) {
    int b = blockIdx.x;
    const float* src; unsigned short* dst;
    if (b < 512)       { src = hs; dst = hsb; }
    else if (b < 1024) { src = Wq; dst = Wcat;                           b -= 512; }
    else if (b < 1152) { src = Wk; dst = Wcat + (size_t)2048 * DMODEL;   b -= 1024; }
    else if (b < 1280) { src = Wv; dst = Wcat + (size_t)2560 * DMODEL;   b -= 1152; }
    else               { src = Wo; dst = Wob;                            b -= 1280; }
    size_t base = (size_t)b * 8192 + threadIdx.x * 4;
#pragma unroll
    for (int it = 0; it < 8; ++it) {
        size_t off = base + (size_t)it * 1024;
        float4 v = *(const float4*)(src + off);
        short4 p;
        p.x = (short)f2bf_rne(v.x); p.y = (short)f2bf_rne(v.y);
        p.z = (short)f2bf_rne(v.z); p.w = (short)f2bf_rne(v.w);
        *(short4*)(dst + off) = p;
    }
}

// ---------------------------------------------------------------------------
// Fused Q/K/V projection, pure bf16, 128x64 tile, BK=128 (2 barriers / 128 k).
// Grid (48, 16) = 768 blocks = 3 blocks/CU (LDS 48 KB).  Wave tile 32x64.
// LDS rows = 256B = 16 chunks of 16B; phys chunk = logical ^ (row&15)
// (4-bit XOR -> conflict-free ds_read_b128, proven round 2).
// ---------------------------------------------------------------------------
__global__ __launch_bounds__(256) void gemm_qkv(const unsigned short* __restrict__ hsb,
                                                const unsigned short* __restrict__ Wcat,
                                                unsigned short* __restrict__ Qo,
                                                unsigned short* __restrict__ Ko,
                                                unsigned short* __restrict__ Vo) {
    __shared__ short Ah[128][128];
    __shared__ short Bh[64][128];

    const int bnx = blockIdx.x;
    int mode, coff;   // 0=Q (32 tiles), 1=K (8), 2=V (8)
    if (bnx < 32)      { mode = 0; coff = bnx * 64; }
    else if (bnx < 40) { mode = 1; coff = (bnx - 32) * 64; }
    else               { mode = 2; coff = (bnx - 40) * 64; }
    const unsigned short* Bbase = Wcat + (size_t)bnx * 64 * DMODEL;

    const int bm = blockIdx.y * 128;
    const int tid = threadIdx.x;
    const int w = tid >> 6, lane = tid & 63;
    const int wA = w * 32, wB = w * 16;
    const int lr = lane & 15, quad = lane >> 4;
    const int r4 = lane >> 4;

    // staging: each GL16 covers rows base + 4g + r4; row&15 = 4*(g&3) + r4.
    // source logical chunk = phys(lane&15) ^ r4 ^ ((g&3)<<2)
    const unsigned short* Ag[4];
    const unsigned short* Bg[4];
#pragma unroll
    for (int gm = 0; gm < 4; ++gm) {
        const int cof = ((lane & 15) ^ r4 ^ (gm << 2)) * 8;
        Ag[gm] = hsb   + (size_t)(bm + wA + 4 * gm + r4) * DMODEL + cof;
        Bg[gm] = Bbase + (size_t)(wB + 4 * gm + r4) * DMODEL + cof;
    }

    floatx4 acc[2][4];
#pragma unroll
    for (int i = 0; i < 2; ++i)
#pragma unroll
        for (int j = 0; j < 4; ++j) acc[i][j] = (floatx4)0.0f;

    for (int k0 = 0; k0 < DMODEL; k0 += 128) {
        __syncthreads();
#pragma unroll
        for (int q = 0; q < 2; ++q)
#pragma unroll
            for (int gm = 0; gm < 4; ++gm)
                GL16(Ag[gm] + (size_t)(16 * q) * DMODEL + k0, &Ah[wA + 16 * q + 4 * gm][0]);
#pragma unroll
        for (int gm = 0; gm < 4; ++gm)
            GL16(Bg[gm] + k0, &Bh[wB + 4 * gm][0]);
        __syncthreads();

#pragma unroll
        for (int s = 0; s < 4; ++s) {
            const int cs = ((s * 4 + quad) ^ lr) * 8;
            shortx8 a0 = *(shortx8*)&Ah[wA + lr][cs];
            shortx8 a1 = *(shortx8*)&Ah[wA + 16 + lr][cs];
            shortx8 bf[4];
#pragma unroll
            for (int j = 0; j < 4; ++j) bf[j] = *(shortx8*)&Bh[j * 16 + lr][cs];
#pragma unroll
            for (int j = 0; j < 4; ++j)
                acc[0][j] = __builtin_amdgcn_mfma_f32_16x16x32_bf16(a0, bf[j], acc[0][j], 0, 0, 0);
#pragma unroll
            for (int j = 0; j < 4; ++j)
                acc[1][j] = __builtin_amdgcn_mfma_f32_16x16x32_bf16(a1, bf[j], acc[1][j], 0, 0, 0);
        }
    }

    // ---- fused RoPE (pair (d,d+32) = acc[i][j], acc[i][j+2], same lane) ----
    if (mode != 2) {
#pragma unroll
        for (int j = 0; j < 2; ++j) {
            float fr = exp2f(-(float)(j * 16 + lr) * (13.2877123795494f / 32.0f));
#pragma unroll
            for (int i = 0; i < 2; ++i) {
                const int row0 = bm + wA + i * 16 + quad * 4;
#pragma unroll
                for (int r = 0; r < 4; ++r) {
                    float s, c;
                    sincosf((float)(row0 + r) * fr, &s, &c);
                    float x1 = acc[i][j][r], x2 = acc[i][j + 2][r];
                    acc[i][j][r]     = x1 * c - x2 * s;
                    acc[i][j + 2][r] = x2 * c + x1 * s;
                }
            }
        }
    }

#pragma unroll
    for (int i = 0; i < 2; ++i) {
        const int row0 = bm + wA + i * 16 + quad * 4;
        if (mode == 0) {           // Q: bf16, pre-scaled by 1/8 (exact)
#pragma unroll
            for (int j = 0; j < 4; ++j) {
                int col = coff + j * 16 + lr;
#pragma unroll
                for (int r = 0; r < 4; ++r)
                    Qo[(size_t)(row0 + r) * DMODEL + col] = f2bf_rne(0.125f * acc[i][j][r]);
            }
        } else if (mode == 1) {    // K: bf16 natural [T][512]
#pragma unroll
            for (int j = 0; j < 4; ++j) {
                int col = coff + j * 16 + lr;
#pragma unroll
                for (int r = 0; r < 4; ++r)
                    Ko[(size_t)(row0 + r) * KVDIM + col] = f2bf_rne(acc[i][j][r]);
            }
        } else {                   // V: bf16 TRANSPOSED [512][T]
#pragma unroll
            for (int j = 0; j < 4; ++j) {
                int col = coff + j * 16 + lr;
                short4 pk;
                pk.x = (short)f2bf_rne(acc[i][j][0]);
                pk.y = (short)f2bf_rne(acc[i][j][1]);
                pk.z = (short)f2bf_rne(acc[i][j][2]);
                pk.w = (short)f2bf_rne(acc[i][j][3]);
                *(short4*)&Vo[(size_t)col * TLEN + row0] = pk;
            }
        }
    }
}

// ---------------------------------------------------------------------------
// MFMA flash attention, m=0 softmax (scores O(5): shift-invariant, exact fp32),
// deferred l-reduction. QBLK=128, 8 waves.
// Round-5 structure: K/V double-buffered, ONE barrier per chunk — next chunk's
// GL16s issued BEFORE computing current chunk (2-phase pipeline, T14/T3-min);
// Q fragments hoisted to registers (wave-private rows, read once);
// Ps group-XOR swizzle (16B groups, group ^= row&7, same involution on write
// and read) to cut the P-scatter/ap bank conflicts.
// LDS: Ks 2x8K + Vs 2x8K + Qs 16K + Ps 18.4K = 66.4 KB -> 2 blocks/CU (= grid).
// ---------------------------------------------------------------------------
__global__ __launch_bounds__(512) void attn_mfma(const unsigned short* __restrict__ Qb,
                                                 const unsigned short* __restrict__ Kb,
                                                 const unsigned short* __restrict__ Vt,
                                                 unsigned short* __restrict__ Ab) {
    __shared__ short Qs[128][64];
    __shared__ short Ks[2][64][64];
    __shared__ short Vs[2][64][64];
    __shared__ short Ps[128][72];   // wave-private rows; swizzled 16B groups

    const int h = blockIdx.y, q0 = blockIdx.x * 128, kvh = h >> 2;
    const int tid = threadIdx.x;
    const int w = tid >> 6, lane = tid & 63;
    const int l15 = lane & 15, quad = lane >> 4;
    const int qw = q0 + w * 16;                   // this wave's first q-row

    // staging lane map: row += lane>>3, phys chunk lane&7,
    // global chunk = (lane&7) ^ ((lane>>3)&7)
    const int sr  = lane >> 3;                    // 0..7
    const int sgc = ((lane & 7) ^ sr) * 8;        // swizzled chunk offset (shorts)

    // chunk range for this block (64-aligned)
    int cb = q0 - WHALF; if (cb < 0) cb = 0;
    int ce = q0 + 128 + WHALF; if (ce > TLEN) ce = TLEN;

    const unsigned short* kbase = Kb + (size_t)(w * 8 + sr) * KVDIM + kvh * HDIM + sgc;
    const unsigned short* vbase = Vt + (size_t)(kvh * HDIM + w * 8 + sr) * TLEN + sgc;

    {   // stage Q tile (wave w: rows w*16 .. w*16+15) + first K/V chunk, buf 0
        const unsigned short* qsrc = Qb + (size_t)(qw + sr) * DMODEL + h * HDIM + sgc;
        GL16(qsrc,              &Qs[w * 16 + 0][0]);
        GL16(qsrc + 8 * DMODEL, &Qs[w * 16 + 8][0]);
        GL16(kbase + (size_t)cb * KVDIM, &Ks[0][w * 8][0]);
        GL16(vbase + cb,                 &Vs[0][w * 8][0]);
    }
    __syncthreads();

    // ---- Q fragment hoist: wave-private rows, read once ----
    shortx8 aq[2];
#pragma unroll
    for (int s = 0; s < 2; ++s) {
        const int cs = ((s * 4 + quad) ^ (l15 & 7)) * 8;
        aq[s] = *(shortx8*)&Qs[w * 16 + l15][cs];
    }

    floatx4 o[4];
#pragma unroll
    for (int j = 0; j < 4; ++j) o[j] = (floatx4)0.0f;
    float l_lane[4] = {0.0f, 0.0f, 0.0f, 0.0f};

    int p = 0;
    for (int ch0 = cb; ch0 < ce; ch0 += 64) {
        // ---- issue next chunk's staging into the other buffer (overlapped) ----
        if (ch0 + 64 < ce) {
            GL16(kbase + (size_t)(ch0 + 64) * KVDIM, &Ks[p ^ 1][w * 8][0]);
            GL16(vbase + (ch0 + 64),                 &Vs[p ^ 1][w * 8][0]);
        }

        // wave-uniform: does this chunk intersect any of this wave's windows?
        if (ch0 >= qw - 319 && ch0 <= qw + 270) {
            // ---- scores: S[16q x 64k] per wave, 8 MFMAs ----
            floatx4 sacc[4];
#pragma unroll
            for (int t = 0; t < 4; ++t) sacc[t] = (floatx4)0.0f;
#pragma unroll
            for (int s = 0; s < 2; ++s) {
                const int cs = ((s * 4 + quad) ^ (l15 & 7)) * 8;
#pragma unroll
                for (int t = 0; t < 4; ++t) {
                    shortx8 bk = *(shortx8*)&Ks[p][t * 16 + l15][cs];
                    sacc[t] = __builtin_amdgcn_mfma_f32_16x16x32_bf16(aq[s], bk, sacc[t], 0, 0, 0);
                }
            }

            // ---- m=0 softmax: mask -> exp -> per-lane l, swizzled P scatter ----
#pragma unroll
            for (int r = 0; r < 4; ++r) {
                const int q = qw + quad * 4 + r;
                const int prow = w * 16 + quad * 4 + r;
                const int rsw = (quad * 4 + r) & 7;            // row&7 (w*16 = 0 mod 8)
#pragma unroll
                for (int t = 0; t < 4; ++t) {
                    const int k = ch0 + t * 16 + l15;
                    bool valid = (k >= q - WHALF) && (k < q + WHALF);
                    float pv = valid ? __expf(sacc[t][r]) : 0.0f;
                    l_lane[r] += pv;
                    const int g = t * 2 + (l15 >> 3);          // 16B group of col t*16+l15
                    Ps[prow][((g ^ rsw) * 8) + (l15 & 7)] = (short)f2bf_rne(pv);
                }
            }

            // ---- PV: O[16q x 64d] += P @ V, 8 MFMAs (Ps rows wave-private) ----
#pragma unroll
            for (int ks = 0; ks < 2; ++ks) {
                const int cs = ((ks * 4 + quad) ^ (l15 & 7)) * 8;
                const int pg = ((ks * 4 + quad) ^ (l15 & 7)) * 8;   // same involution
                shortx8 ap = *(shortx8*)&Ps[w * 16 + l15][pg];
#pragma unroll
                for (int j = 0; j < 4; ++j) {
                    shortx8 bv = *(shortx8*)&Vs[p][j * 16 + l15][cs];
                    o[j] = __builtin_amdgcn_mfma_f32_16x16x32_bf16(ap, bv, o[j], 0, 0, 0);
                }
            }
        }

        // one barrier per chunk: drains this wave's GL16s (next buf ready for
        // all) and ensures everyone is done reading buf p before overwrite.
        __syncthreads();
        p ^= 1;
    }

    // ---- epilogue: one l-reduction per row, divide, store bf16 ----
#pragma unroll
    for (int r = 0; r < 4; ++r) {
        float l = l_lane[r];
#pragma unroll
        for (int mb = 1; mb < 16; mb <<= 1)
            l += __shfl_xor(l, mb, 64);
        float inv = 1.0f / l;
        const int q = qw + quad * 4 + r;
#pragma unroll
        for (int j = 0; j < 4; ++j)
            Ab[(size_t)q * DMODEL + h * HDIM + j * 16 + l15] = f2bf_rne(o[j][r] * inv);
    }
}

// ---------------------------------------------------------------------------
// Output projection, 128x64 tile, BK=128, 4-bit XOR swizzle.
// Grid (32, 16) = 512 blocks. C fp32 = Ab @ Wob^T.
// ---------------------------------------------------------------------------
__global__ __launch_bounds__(256) void gemm_oproj(const unsigned short* __restrict__ Ab,
                                                  const unsigned short* __restrict__ Wob,
                                                  float* __restrict__ C) {
    __shared__ short Ah[128][128];
    __shared__ short Bh[64][128];

    const int bm = blockIdx.y * 128, bn = blockIdx.x * 64;
    const int tid = threadIdx.x;
    const int w = tid >> 6, lane = tid & 63;
    const int wA = w * 32, wB = w * 16;
    const int lr = lane & 15, quad = lane >> 4;
    const int r4 = lane >> 4;

    const unsigned short* Ag[4];
    const unsigned short* Bg[4];
#pragma unroll
    for (int gm = 0; gm < 4; ++gm) {
        const int cof = ((lane & 15) ^ r4 ^ (gm << 2)) * 8;
        Ag[gm] = Ab  + (size_t)(bm + wA + 4 * gm + r4) * DMODEL + cof;
        Bg[gm] = Wob + (size_t)(bn + wB + 4 * gm + r4) * DMODEL + cof;
    }

    floatx4 acc[2][4];
#pragma unroll
    for (int i = 0; i < 2; ++i)
#pragma unroll
        for (int j = 0; j < 4; ++j) acc[i][j] = (floatx4)0.0f;

    for (int k0 = 0; k0 < DMODEL; k0 += 128) {
        __syncthreads();
#pragma unroll
        for (int q = 0; q < 2; ++q)
#pragma unroll
            for (int gm = 0; gm < 4; ++gm)
                GL16(Ag[gm] + (size_t)(16 * q) * DMODEL + k0, &Ah[wA + 16 * q + 4 * gm][0]);
#pragma unroll
        for (int gm = 0; gm < 4; ++gm)
            GL16(Bg[gm] + k0, &Bh[wB + 4 * gm][0]);
        __syncthreads();

#pragma unroll
        for (int s = 0; s < 4; ++s) {
            const int cs = ((s * 4 + quad) ^ lr) * 8;
            shortx8 a0 = *(shortx8*)&Ah[wA + lr][cs];
            shortx8 a1 = *(shortx8*)&Ah[wA + 16 + lr][cs];
            shortx8 bf[4];
#pragma unroll
            for (int j = 0; j < 4; ++j) bf[j] = *(shortx8*)&Bh[j * 16 + lr][cs];
#pragma unroll
            for (int j = 0; j < 4; ++j)
                acc[0][j] = __builtin_amdgcn_mfma_f32_16x16x32_bf16(a0, bf[j], acc[0][j], 0, 0, 0);
#pragma unroll
            for (int j = 0; j < 4; ++j)
                acc[1][j] = __builtin_amdgcn_mfma_f32_16x16x32_bf16(a1, bf[j], acc[1][j], 0, 0, 0);
        }
    }

#pragma unroll
    for (int i = 0; i < 2; ++i) {
        const int row0 = bm + wA + i * 16 + quad * 4;
#pragma unroll
        for (int j = 0; j < 4; ++j) {
            int col = bn + j * 16 + lr;
#pragma unroll
            for (int r = 0; r < 4; ++r)
                C[(size_t)(row0 + r) * DMODEL + col] = acc[i][j][r];
        }
    }
}

// ---------------------------------------------------------------------------
extern "C" void kernel_launch(void* const* d_in, const int* in_sizes, int n_in,
                              void* d_out, int out_size, void* d_ws, size_t ws_size,
                              hipStream_t stream) {
    const float* hs = (const float*)d_in[0];
    const float* Wq = (const float*)d_in[1];
    const float* Wk = (const float*)d_in[2];
    const float* Wv = (const float*)d_in[3];
    const float* Wo = (const float*)d_in[4];
    float* out = (float*)d_out;

    // workspace: ~42 MB bf16. hsb buffer reused as Ab.
    unsigned short* Qb   = (unsigned short*)d_ws;            // [T][2048] rotated, /8
    unsigned short* Kb   = Qb + (size_t)TLEN * DMODEL;       // [T][512]  rotated
    unsigned short* Vt   = Kb + (size_t)TLEN * KVDIM;        // [512][T]  transposed
    unsigned short* hsAb = Vt + (size_t)KVDIM * TLEN;        // [T][2048] hs bf16, then attn out
    unsigned short* Wcat = hsAb + (size_t)TLEN * DMODEL;     // [3072][2048] {Wq;Wk;Wv} bf16
    unsigned short* Wob  = Wcat + (size_t)3072 * DMODEL;     // [2048][2048] Wo bf16

    dim3 blk(256);

    convert_inputs<<<1792, blk, 0, stream>>>(hs, Wq, Wk, Wv, Wo, hsAb, Wcat, Wob);

    gemm_qkv<<<dim3(48, TLEN / 128), blk, 0, stream>>>(hsAb, Wcat, Qb, Kb, Vt);

    attn_mfma<<<dim3(TLEN / 128, NHEADS), dim3(512), 0, stream>>>(Qb, Kb, Vt, hsAb);

    gemm_oproj<<<dim3(DMODEL / 64, TLEN / 128), blk, 0, stream>>>(hsAb, Wob, out);
}